// Round 2
// baseline (567.989 us; speedup 1.0000x reference)
//
#include <hip/hip_runtime.h>
#include <stdint.h>

// TPTransMatrix: out = x (16384 x 4096) times block_diag(blocks[0..7]),
// blocks[kb] 512x512 fp32. Grouped bf16-MFMA GEMM, M=16384 K=512 N=512 x8.
// R2: single-barrier dbuf-pipelined K-loop + full-line float4 epilogue + XCD swizzle.

#define HID 4096
#define KD  512
#define NKB 8
#define BM  128
#define BN  128
#define BK  32
#define MTILES 128              // 16384 / BM
#define ASTRIDE 40              // A LDS row stride in uint16 (80 B = 64 used + 16 pad)
#define LAHALF (BM * ASTRIDE)   // 5120 uint16 per A buffer
#define LBHALF (BN * BK)        // 4096 uint16 per B buffer
#define NIT (KD / BK)           // 16

typedef __attribute__((ext_vector_type(4))) float    f32x4;
typedef __attribute__((ext_vector_type(8))) short    s16x8;
typedef __attribute__((ext_vector_type(4))) uint32_t u32x4;

// bf16 transposed blocks: g_bt[kb][c][b] = bf16(blocks[kb][b][c])
__device__ uint16_t g_bt[(size_t)NKB * KD * KD];

__device__ __forceinline__ void async_copy16(const void* g, void* l) {
  __builtin_amdgcn_global_load_lds((const __attribute__((address_space(1))) void*)g,
                                   (__attribute__((address_space(3))) void*)l,
                                   16, 0, 0);
}

__device__ __forceinline__ uint16_t f2bf_rne(float f) {
  uint32_t u = __float_as_uint(f);
  u += 0x7fffu + ((u >> 16) & 1u);
  return (uint16_t)(u >> 16);
}

// ---------------- prep: transpose + convert blocks -> g_bt ----------------
__global__ void convert_blocks_k(const float* __restrict__ blocks) {
  __shared__ float tile[32][33];
  const int kb = blockIdx.z;
  const int c0 = blockIdx.x * 32;
  const int b0 = blockIdx.y * 32;
  const int tx = threadIdx.x;   // 0..31
  const int ty = threadIdx.y;   // 0..7
  const float* src = blocks + ((size_t)kb * KD + b0) * KD + c0;
#pragma unroll
  for (int i = 0; i < 4; ++i) {
    const int r = ty + i * 8;
    tile[r][tx] = src[(size_t)r * KD + tx];
  }
  __syncthreads();
  uint16_t* dst = g_bt + ((size_t)kb * KD + c0) * KD + b0;
#pragma unroll
  for (int i = 0; i < 4; ++i) {
    const int r = ty + i * 8;
    dst[(size_t)r * KD + tx] = f2bf_rne(tile[tx][r]);
  }
}

// ---------------- main grouped GEMM ----------------
__global__ void __launch_bounds__(256, 4)
grouped_gemm_k(const float* __restrict__ x, float* __restrict__ out) {
  // 2*A(10240B) + 2*B(8192B) = 36864 B; epilogue reuses the same memory (17408 B).
  __shared__ uint16_t smem[2 * LAHALF + 2 * LBHALF];
  uint16_t* lA = smem;                 // [2][LAHALF]
  uint16_t* lB = smem + 2 * LAHALF;    // [2][LBHALF]

  const int tid = threadIdx.x;
  // XCD swizzle: consecutive blockIdx round-robin XCDs; make the 4 nt-tiles that
  // share an A-slice land consecutively on the SAME XCD for L2 sharing.
  const int bid = blockIdx.x;
  const int j   = (bid & 7) * (MTILES * NKB * 4 / 8) + (bid >> 3);
  const int nt  =  j       & 3;
  const int kb  = (j >> 2) & 7;
  const int mt  =  j >> 5;

  const int wave = tid >> 6;
  const int lane = tid & 63;
  const int ln   = lane & 15;
  const int qd   = lane >> 4;
  const int wm   = (wave & 1) * 64;
  const int wn   = (wave >> 1) * 64;

  // ---- A staging: thread -> (row am, k-half ah), 16 consecutive floats ----
  const int am = tid >> 1;
  const int ah = tid & 1;
  const float* aptr = x + (size_t)(mt * BM + am) * HID + kb * KD + ah * 16;
  uint16_t* awr = lA + am * ASTRIDE + ah * 16;

  // ---- B staging: global-side xor swizzle (lds dst must be lane-contiguous) ----
  const int bn0 = tid >> 2;
  const int bs0 = (tid & 3) ^ (bn0 & 3) ^ ((bn0 >> 2) & 3);
  const int p1  = tid + 256;
  const int bn1 = p1 >> 2;
  const int bs1 = (p1 & 3) ^ (bn1 & 3) ^ ((bn1 >> 2) & 3);
  const uint16_t* bsrc0 = g_bt + (size_t)(kb * KD + nt * BN + bn0) * KD + bs0 * 8;
  const uint16_t* bsrc1 = g_bt + (size_t)(kb * KD + nt * BN + bn1) * KD + bs1 * 8;
  uint16_t* bdst0 = lB + tid * 8;
  uint16_t* bdst1 = lB + p1 * 8;

  // ---- fragment read bases ----
  const int sw = (ln & 3) ^ ((ln >> 2) & 3);
  const uint16_t* ard = lA + (wm + ln) * ASTRIDE + qd * 8;
  const uint16_t* brd = lB + ((wn + ln) * 4 + (qd ^ sw)) * 8;

  f32x4 acc[4][4];
#pragma unroll
  for (int mi = 0; mi < 4; ++mi)
#pragma unroll
    for (int ni = 0; ni < 4; ++ni)
      acc[mi][ni] = (f32x4){0.f, 0.f, 0.f, 0.f};

  // ---- prologue: stage k=0 into buffer 0 ----
  {
    async_copy16(bsrc0, bdst0);
    async_copy16(bsrc1, bdst1);
    const f32x4 a0 = *(const f32x4*)(aptr);
    const f32x4 a1 = *(const f32x4*)(aptr + 4);
    const f32x4 a2 = *(const f32x4*)(aptr + 8);
    const f32x4 a3 = *(const f32x4*)(aptr + 12);
    u32x4 w0, w1;
    w0.x = __builtin_amdgcn_perm(__float_as_uint(a0.y), __float_as_uint(a0.x), 0x07060302u);
    w0.y = __builtin_amdgcn_perm(__float_as_uint(a0.w), __float_as_uint(a0.z), 0x07060302u);
    w0.z = __builtin_amdgcn_perm(__float_as_uint(a1.y), __float_as_uint(a1.x), 0x07060302u);
    w0.w = __builtin_amdgcn_perm(__float_as_uint(a1.w), __float_as_uint(a1.z), 0x07060302u);
    w1.x = __builtin_amdgcn_perm(__float_as_uint(a2.y), __float_as_uint(a2.x), 0x07060302u);
    w1.y = __builtin_amdgcn_perm(__float_as_uint(a2.w), __float_as_uint(a2.z), 0x07060302u);
    w1.z = __builtin_amdgcn_perm(__float_as_uint(a3.y), __float_as_uint(a3.x), 0x07060302u);
    w1.w = __builtin_amdgcn_perm(__float_as_uint(a3.w), __float_as_uint(a3.z), 0x07060302u);
    *(u32x4*)(awr)     = w0;
    *(u32x4*)(awr + 8) = w1;
  }

  // ---- pipelined K-loop: ONE barrier per iter; prefetch depth 1 ----
  for (int k = 0; k < NIT; ++k) {
    const int cur = k & 1;
    const int nxt = cur ^ 1;
    __syncthreads();   // vmcnt drain covers loads issued a full iteration ago

    f32x4 a0, a1, a2, a3;
    if (k < NIT - 1) {
      const int k1 = (k + 1) * BK;
      async_copy16(bsrc0 + k1, bdst0 + nxt * LBHALF);
      async_copy16(bsrc1 + k1, bdst1 + nxt * LBHALF);
      a0 = *(const f32x4*)(aptr + k1);
      a1 = *(const f32x4*)(aptr + k1 + 4);
      a2 = *(const f32x4*)(aptr + k1 + 8);
      a3 = *(const f32x4*)(aptr + k1 + 12);
    }

    const uint16_t* ar = ard + cur * LAHALF;
    const uint16_t* br = brd + cur * LBHALF;
    s16x8 af[4], bf[4];
#pragma unroll
    for (int mi = 0; mi < 4; ++mi) af[mi] = *(const s16x8*)(ar + mi * (16 * ASTRIDE));
#pragma unroll
    for (int ni = 0; ni < 4; ++ni) bf[ni] = *(const s16x8*)(br + ni * (16 * 32));
#pragma unroll
    for (int mi = 0; mi < 4; ++mi)
#pragma unroll
      for (int ni = 0; ni < 4; ++ni)
        acc[mi][ni] = __builtin_amdgcn_mfma_f32_16x16x32_bf16(af[mi], bf[ni], acc[mi][ni], 0, 0, 0);

    if (k < NIT - 1) {
      u32x4 w0, w1;
      w0.x = __builtin_amdgcn_perm(__float_as_uint(a0.y), __float_as_uint(a0.x), 0x07060302u);
      w0.y = __builtin_amdgcn_perm(__float_as_uint(a0.w), __float_as_uint(a0.z), 0x07060302u);
      w0.z = __builtin_amdgcn_perm(__float_as_uint(a1.y), __float_as_uint(a1.x), 0x07060302u);
      w0.w = __builtin_amdgcn_perm(__float_as_uint(a1.w), __float_as_uint(a1.z), 0x07060302u);
      w1.x = __builtin_amdgcn_perm(__float_as_uint(a2.y), __float_as_uint(a2.x), 0x07060302u);
      w1.y = __builtin_amdgcn_perm(__float_as_uint(a2.w), __float_as_uint(a2.z), 0x07060302u);
      w1.z = __builtin_amdgcn_perm(__float_as_uint(a3.y), __float_as_uint(a3.x), 0x07060302u);
      w1.w = __builtin_amdgcn_perm(__float_as_uint(a3.w), __float_as_uint(a3.z), 0x07060302u);
      *(u32x4*)(awr + nxt * LAHALF)     = w0;
      *(u32x4*)(awr + nxt * LAHALF + 8) = w1;
    }
  }

  // ---- epilogue: per-wave LDS transpose -> full-line float4 stores ----
  __syncthreads();   // everyone done reading K-loop LDS before we overwrite it
  float* eb = (float*)smem + wave * (16 * 68);   // 16 rows x 68-float stride, 4352 B/wave
  const int rr = lane >> 4;                      // 0..3  (row within 4-row store group)
  const int cs = (lane & 15) * 4;                // col within 64, float4 granule
  const int colb = kb * KD + nt * BN + wn + cs;
#pragma unroll
  for (int mi = 0; mi < 4; ++mi) {
    // scatter acc[mi] into LDS: local row = qd*4+r (stride 68 -> 2-way banks, free)
#pragma unroll
    for (int ni = 0; ni < 4; ++ni)
#pragma unroll
      for (int r = 0; r < 4; ++r)
        eb[(qd * 4 + r) * 68 + ln + ni * 16] = acc[mi][ni][r];
    // gather rows as float4 and store full 256B row-segments
#pragma unroll
    for (int sub = 0; sub < 4; ++sub) {
      const f32x4 v = *(const f32x4*)(eb + (sub * 4 + rr) * 68 + cs);
      const int row = mt * BM + wm + mi * 16 + sub * 4 + rr;
      *(f32x4*)(out + (size_t)row * HID + colb) = v;
    }
  }
}

extern "C" void kernel_launch(void* const* d_in, const int* in_sizes, int n_in,
                              void* d_out, int out_size, void* d_ws, size_t ws_size,
                              hipStream_t stream) {
  const float* x      = (const float*)d_in[0];   // [4,4096,4096] fp32
  const float* blocks = (const float*)d_in[1];   // [8,512,512] fp32
  float* out = (float*)d_out;
  (void)d_ws; (void)ws_size; (void)in_sizes; (void)n_in; (void)out_size;

  convert_blocks_k<<<dim3(16, 16, 8), dim3(32, 8, 1), 0, stream>>>(blocks);
  grouped_gemm_k<<<dim3(MTILES * NKB * 4, 1, 1), dim3(256, 1, 1), 0, stream>>>(x, out);
}